// Round 1
// baseline (583.850 us; speedup 1.0000x reference)
//
#include <hip/hip_runtime.h>
#include <hip/hip_bf16.h>
#include <stdint.h>

#define NBATCH 2
#define NCH    256
#define NTOK   4096
#define NINT   64
#define CHW    64            // staged chunk width (columns)
#define QCOLS  1024          // columns per quarter-block
#define NCHQ   (QCOLS/CHW)   // 16 chunks per quarter

typedef float  f32x4  __attribute__((ext_vector_type(4)));
typedef __bf16 bf16x8 __attribute__((ext_vector_type(8)));
union U16x8 { uint4 u; bf16x8 b; };

// ---- workspace layout (bytes) ----
// per batch, 10 bf16 arrays of [4096][64]: 0 QS_h 1 QS_l 2 KS_h 3 KS_l
// 4 QC_h 5 QC_l 6 KC_h 7 KC_l 8 VS 9 VC
#define SZBF      ((size_t)NTOK*NINT)
#define BF_TOTAL  ((size_t)NBATCH*10*SZBF*2)
#define FEAT_OFF  (BF_TOTAL)          // feat [4 bbr][4096][64] fp32
// rL (4 bbr x 4096 f32 = 64 KB) overlays V_s of b=0 — dead after k_s1,
// rewritten by k_proj next iteration. No extra ws bytes needed.
#define RL_OFF_B  ((size_t)4194304)

#define OUT_SELF  ((size_t)2097152)
#define OUT_CROSS ((size_t)35651584)
// scratch inside the score_self output region (fully overwritten by k_s2):
#define FPART_OFF_F (OUT_SELF)                     // [4 bbr][4 qtr][4096][64] f32 = 16 MB
#define LPART_OFF_F (OUT_SELF + (size_t)4194304)   // [4 bbr][4 qtr][4096] f32 = 256 KB

__device__ inline unsigned short f2bf(float x){
  unsigned int u = __builtin_bit_cast(unsigned int, x);
  u = (u + 0x7FFFu + ((u>>16)&1u)) >> 16;
  return (unsigned short)u;
}
__device__ inline float bf2f(unsigned short s){
  unsigned int u = ((unsigned int)s)<<16;
  return __builtin_bit_cast(float, u);
}

typedef __attribute__((address_space(3))) unsigned int lds_u32_t;
typedef __attribute__((address_space(1))) const unsigned int gbl_u32_t;
__device__ inline void async16(const void* g, void* l){
  __builtin_amdgcn_global_load_lds((gbl_u32_t*)g, (lds_u32_t*)l, 16, 0, 0);
}

// ---------------- kernel 1: masked projections (fp32) ----------------
__global__ __launch_bounds__(256) void k_proj(
    const float* __restrict__ x, const float* __restrict__ mask,
    const float* __restrict__ wts, const float* __restrict__ wps,
    const float* __restrict__ wgs, const float* __restrict__ wtc,
    const float* __restrict__ wpc, const float* __restrict__ wgc,
    char* __restrict__ ws)
{
  int nt = blockIdx.x;    // 64 n-tiles of 64
  int j  = blockIdx.y;    // which matrix
  int b  = blockIdx.z;
  const float* W; int isBg, mode, arrH, arrL;
  switch (j) {
    case 0: W=wts; isBg=0; mode=0; arrH=2; arrL=3; break; // K_s
    case 1: W=wps; isBg=0; mode=0; arrH=0; arrL=1; break; // Q_s
    case 2: W=wgs; isBg=0; mode=1; arrH=8; arrL=8; break; // V_s
    case 3: W=wpc; isBg=0; mode=0; arrH=4; arrL=5; break; // Q_c
    case 4: W=wtc; isBg=1; mode=0; arrH=6; arrL=7; break; // K_c
    default:W=wgc; isBg=1; mode=1; arrH=9; arrL=9; break; // V_c
  }
  __shared__ float xm[256*64];
  __shared__ float msk[64];
  int t = threadIdx.x;
  if (t < 64) {
    float m = mask[(size_t)b*NTOK + nt*64 + t];
    msk[t] = isBg ? (1.0f - m) : m;
  }
  __syncthreads();
  const float* xb = x + (size_t)b*NCH*NTOK + nt*64;
  for (int it = 0; it < 64; ++it) {
    int flat = it*256 + t; int c = flat>>6, nl = flat&63;
    xm[flat] = xb[(size_t)c*NTOK + nl] * msk[nl];
  }
  __syncthreads();
  int nl = t & 63;
  int o0 = __builtin_amdgcn_readfirstlane((t>>6)*16);
  const float* Wr = W + (size_t)o0*256;
  float acc[16];
  #pragma unroll
  for (int i=0;i<16;i++) acc[i]=0.0f;
  #pragma unroll 4
  for (int c=0;c<256;c++){
    float xv = xm[c*64+nl];
    #pragma unroll
    for (int i=0;i<16;i++) acc[i] += Wr[i*256 + c] * xv;
  }
  int n = nt*64 + nl;
  if (mode==0){
    unsigned short* Ah = (unsigned short*)ws + ((size_t)b*10 + arrH)*SZBF;
    unsigned short* Al = (unsigned short*)ws + ((size_t)b*10 + arrL)*SZBF;
    #pragma unroll
    for (int i=0;i<16;i++){
      float v = acc[i];
      unsigned short h = f2bf(v);
      float r = v - bf2f(h);
      Ah[(size_t)n*NINT + o0+i] = h;
      Al[(size_t)n*NINT + o0+i] = f2bf(r);
    }
  } else {
    unsigned short* V = (unsigned short*)ws + ((size_t)b*10 + arrH)*SZBF;
    #pragma unroll
    for (int i=0;i<16;i++) V[(size_t)(o0+i)*NTOK + n] = f2bf(acc[i]);
  }
}

// ---------------- kernel 2a: sweep 1 on quarter-column blocks ----------------
// 1024 blocks = 4 bbr x 64 mb x 4 qtr; 256 thr = 4 waves (one 16-row m-tile
// each), 1024 cols per block. LDS 41.9 KB -> 3 blocks/CU = 12 waves/CU with
// independent 4-wave barrier domains. One barrier per round. Writes
// UNNORMALIZED feat partials + L partials into the (dead) score_self region.
__global__ __launch_bounds__(256) void k_s1(char* __restrict__ ws, float* __restrict__ out)
{
  __shared__ __align__(16) char smem[41984]; // 2 x 16384 K dbuf + 4 x 2304 lP

  int blk = blockIdx.x;
  int xcd = blk & 7, idx = blk >> 3;
  int bbr = xcd >> 1;                  // 2 XCDs per (b,branch): K/V/Q L2-resident
  int unit = ((xcd & 1) << 7) | idx;   // 0..255
  int qtr = unit & 3, mb = unit >> 2;
  int b = bbr >> 1, br = bbr & 1;
  const unsigned short* Qh = (const unsigned short*)ws + ((size_t)b*10 + (br?4:0))*SZBF;
  const unsigned short* Ql = Qh + SZBF;
  const unsigned short* Kh = (const unsigned short*)ws + ((size_t)b*10 + (br?6:2))*SZBF;
  const unsigned short* Kl = Kh + SZBF;
  const unsigned short* Vv = (const unsigned short*)ws + ((size_t)b*10 + (br?9:8))*SZBF;

  int t = threadIdx.x, lane = t&63, w = t>>6;   // w = m-tile
  int rowb = lane&15, q4 = lane>>4, ko = q4*8;
  int m0 = mb*64 + w*16, mrow = m0 + rowb;

  unsigned short* lPw = (unsigned short*)(smem + 32768 + w*2304);

  U16x8 qh[2], ql[2];
  #pragma unroll
  for (int kk=0;kk<2;kk++){
    qh[kk].u = *(const uint4*)(Qh + (size_t)mrow*NINT + kk*32 + ko);
    ql[kk].u = *(const uint4*)(Ql + (size_t)mrow*NINT + kk*32 + ko);
  }

  auto lkbase = [&](int buf)->unsigned short*{
    return (unsigned short*)(smem + (size_t)buf*16384);
  };
  // stage one 64-col K chunk (KH 8KB + KL 8KB), XOR-swizzled source
  auto stage = [&](int ch, int buf){
    int n0 = qtr*QCOLS + ch*CHW;
    const unsigned short* gH = Kh + (size_t)n0*NINT;
    const unsigned short* gL = Kl + (size_t)n0*NINT;
    unsigned short* LB = lkbase(buf);
    #pragma unroll
    for (int it=0; it<2; ++it){
      int f = it*256 + t;             // granule 0..511
      int r = f>>3, g = f&7, gs = g ^ (r&7);
      size_t goff = (size_t)r*64 + gs*8;
      async16(gH + goff, LB + (size_t)f*8);
      async16(gL + goff, LB + 4096 + (size_t)f*8);
    }
  };

  f32x4 fac[4];
  #pragma unroll
  for (int ot=0;ot<4;ot++) fac[ot] = (f32x4){0.0f,0.0f,0.0f,0.0f};
  float Lacc = 0.0f;

  stage(0, 0);
  for (int ch=0; ch<NCHQ; ++ch){
    int cur = ch & 1;
    asm volatile("s_waitcnt vmcnt(0)" ::: "memory");
    __syncthreads();
    if (ch+1 < NCHQ) stage(ch+1, cur^1);
    unsigned short* LB = lkbase(cur);
    int n0 = qtr*QCOLS + ch*CHW;
    #pragma unroll
    for (int t8=0; t8<4; ++t8){
      int row = t8*16 + rowb;
      f32x4 s = {0.0f,0.0f,0.0f,0.0f};
      #pragma unroll
      for (int kk=0; kk<2; ++kk){
        int soff = row*64 + (((kk*4 + q4) ^ (row&7))*8);
        U16x8 ah, al;
        ah.u = *(const uint4*)(LB + soff);
        al.u = *(const uint4*)(LB + 4096 + soff);
        s = __builtin_amdgcn_mfma_f32_16x16x32_bf16(ah.b, qh[kk].b, s, 0,0,0);
        s = __builtin_amdgcn_mfma_f32_16x16x32_bf16(ah.b, ql[kk].b, s, 0,0,0);
        s = __builtin_amdgcn_mfma_f32_16x16x32_bf16(al.b, qh[kk].b, s, 0,0,0);
      }
      float p0=__expf(s[0]), p1=__expf(s[1]), p2=__expf(s[2]), p3=__expf(s[3]);
      Lacc += (p0+p1)+(p2+p3);
      unsigned int lo = (unsigned int)f2bf(p0) | ((unsigned int)f2bf(p1)<<16);
      unsigned int hi = (unsigned int)f2bf(p2) | ((unsigned int)f2bf(p3)<<16);
      uint2 pk; pk.x = lo; pk.y = hi;
      *(uint2*)(lPw + rowb*72 + t8*16 + q4*4) = pk;
    }
    asm volatile("s_waitcnt lgkmcnt(0)" ::: "memory");
    #pragma unroll
    for (int kk4=0; kk4<2; ++kk4){
      U16x8 pa;
      pa.u = *(const uint4*)(lPw + rowb*72 + kk4*32 + ko);
      #pragma unroll
      for (int ot=0; ot<4; ++ot){
        U16x8 vb;
        vb.u = *(const uint4*)(Vv + (size_t)(ot*16+rowb)*NTOK + n0 + kk4*32 + ko);
        fac[ot] = __builtin_amdgcn_mfma_f32_16x16x32_bf16(pa.b, vb.b, fac[ot], 0,0,0);
      }
    }
    asm volatile("s_waitcnt lgkmcnt(0)" ::: "memory");
    // single barrier per round (top of next iteration) is sufficient: all LDS
    // reads are consumed (lgkm-waited) before any wave can reach that barrier.
  }

  // ---- per-row partial L (this quarter) ----
  #pragma unroll
  for (int d=16; d<64; d<<=1) Lacc += __shfl_xor(Lacc, d, 64);
  if (q4==0)
    out[LPART_OFF_F + (size_t)(bbr*4+qtr)*NTOK + m0 + rowb] = Lacc;

  // ---- unnormalized feat partial (this quarter) ----
  float* FP = out + FPART_OFF_F + (size_t)(bbr*4+qtr)*NTOK*NINT;
  #pragma unroll
  for (int ot=0; ot<4; ++ot)
    #pragma unroll
    for (int r=0; r<4; ++r)
      FP[(size_t)(m0 + q4*4 + r)*NINT + ot*16 + rowb] = fac[ot][r];
}

// ---------------- kernel 2b: combine quarters -> feat, 1/L ----------------
__global__ __launch_bounds__(256) void k_comb(char* __restrict__ ws, float* __restrict__ out)
{
  int blk = blockIdx.x;
  int bbr = blk >> 6, mb = blk & 63;
  const float* FP = out + FPART_OFF_F;
  const float* LP = out + LPART_OFF_F;
  float* feat = (float*)(ws + FEAT_OFF) + (size_t)bbr*NTOK*NINT;
  float* rL = (float*)(ws + RL_OFF_B) + (size_t)bbr*NTOK;
  int t = threadIdx.x;
  __shared__ float rls[64];
  if (t < 64) {
    int row = mb*64 + t;
    float L = 0.0f;
    #pragma unroll
    for (int q=0;q<4;q++) L += LP[(size_t)(bbr*4+q)*NTOK + row];
    float r = 1.0f / L;
    rls[t] = r;
    rL[row] = r;
  }
  __syncthreads();
  int o = t & 63, rg = t >> 6;
  for (int it=0; it<16; ++it){
    int rloc = it*4 + rg, row = mb*64 + rloc;
    float s = 0.0f;
    #pragma unroll
    for (int q=0;q<4;q++)
      s += FP[((size_t)(bbr*4+q)*NTOK + row)*NINT + o];
    feat[(size_t)row*NINT + o] = s * rls[rloc];
  }
}

// ---------------- kernel 2c: sweep 2, write P = exp(S)/L ----------------
// Same quarter decomposition; no lP/PV -> LDS 32 KB -> 4 blocks/CU =
// 16 waves/CU. Counted vmcnt(4): exactly 4 nt-stores are issued after each
// stage (order pinned by sched_barrier), so store-acks of the 268 MB output
// never block the next round — only the 4 staging loads do.
__global__ __launch_bounds__(256) void k_s2(const char* __restrict__ ws, float* __restrict__ out)
{
  __shared__ __align__(16) char smem[32768]; // 2 x 16384 K dbuf

  int blk = blockIdx.x;
  int xcd = blk & 7, idx = blk >> 3;
  int bbr = xcd >> 1;
  int unit = ((xcd & 1) << 7) | idx;
  int qtr = unit & 3, mb = unit >> 2;
  int b = bbr >> 1, br = bbr & 1;
  const unsigned short* Qh = (const unsigned short*)ws + ((size_t)b*10 + (br?4:0))*SZBF;
  const unsigned short* Ql = Qh + SZBF;
  const unsigned short* Kh = (const unsigned short*)ws + ((size_t)b*10 + (br?6:2))*SZBF;
  const unsigned short* Kl = Kh + SZBF;

  int t = threadIdx.x, lane = t&63, w = t>>6;
  int rowb = lane&15, q4 = lane>>4, ko = q4*8;
  int m0 = mb*64 + w*16, mrow = m0 + rowb;

  float rLp = ((const float*)(ws + RL_OFF_B))[(size_t)bbr*NTOK + mrow];

  U16x8 qh[2], ql[2];
  #pragma unroll
  for (int kk=0;kk<2;kk++){
    qh[kk].u = *(const uint4*)(Qh + (size_t)mrow*NINT + kk*32 + ko);
    ql[kk].u = *(const uint4*)(Ql + (size_t)mrow*NINT + kk*32 + ko);
  }

  auto lkbase = [&](int buf)->unsigned short*{
    return (unsigned short*)(smem + (size_t)buf*16384);
  };
  auto stage = [&](int ch, int buf){
    int n0 = qtr*QCOLS + ch*CHW;
    const unsigned short* gH = Kh + (size_t)n0*NINT;
    const unsigned short* gL = Kl + (size_t)n0*NINT;
    unsigned short* LB = lkbase(buf);
    #pragma unroll
    for (int it=0; it<2; ++it){
      int f = it*256 + t;
      int r = f>>3, g = f&7, gs = g ^ (r&7);
      size_t goff = (size_t)r*64 + gs*8;
      async16(gH + goff, LB + (size_t)f*8);
      async16(gL + goff, LB + 4096 + (size_t)f*8);
    }
  };

  float* outS = out + (br ? OUT_CROSS : OUT_SELF) + (size_t)b*NTOK*NTOK;

  stage(0, 0);
  for (int ch=0; ch<NCHQ; ++ch){
    int cur = ch & 1;
    if (ch == 0) { asm volatile("s_waitcnt vmcnt(0)" ::: "memory"); }
    else         { asm volatile("s_waitcnt vmcnt(4)" ::: "memory"); }
    __syncthreads();
    if (ch+1 < NCHQ) stage(ch+1, cur^1);
    __builtin_amdgcn_sched_barrier(0);   // pin: stage loads before this round's stores
    unsigned short* LB = lkbase(cur);
    int n0 = qtr*QCOLS + ch*CHW;
    #pragma unroll
    for (int t8=0; t8<4; ++t8){
      int row = t8*16 + rowb;
      f32x4 s = {0.0f,0.0f,0.0f,0.0f};
      #pragma unroll
      for (int kk=0; kk<2; ++kk){
        int soff = row*64 + (((kk*4 + q4) ^ (row&7))*8);
        U16x8 ah, al;
        ah.u = *(const uint4*)(LB + soff);
        al.u = *(const uint4*)(LB + 4096 + soff);
        s = __builtin_amdgcn_mfma_f32_16x16x32_bf16(ah.b, qh[kk].b, s, 0,0,0);
        s = __builtin_amdgcn_mfma_f32_16x16x32_bf16(ah.b, ql[kk].b, s, 0,0,0);
        s = __builtin_amdgcn_mfma_f32_16x16x32_bf16(al.b, qh[kk].b, s, 0,0,0);
      }
      f32x4 p;
      p[0] = __expf(s[0])*rLp; p[1] = __expf(s[1])*rLp;
      p[2] = __expf(s[2])*rLp; p[3] = __expf(s[3])*rLp;
      __builtin_nontemporal_store(p,
          (f32x4*)(outS + (size_t)mrow*NTOK + n0 + t8*16 + q4*4));
    }
  }
}

// ---------------- kernel 3: epilogue out = x + w_out @ (fs+fc) ----------------
__global__ __launch_bounds__(256) void k_epi(
    const float* __restrict__ x, const float* __restrict__ wout,
    const char* __restrict__ ws, float* __restrict__ out)
{
  int nt = blockIdx.x, b = blockIdx.y;
  int t = threadIdx.x, nl = t&63;
  const float* feat = (const float*)(ws + FEAT_OFF);
  __shared__ float fs[64][65];
  for (int it=0; it<16; ++it){
    int flat = it*256 + t; int n_l = flat>>6, o = flat&63;
    size_t r0 = ((size_t)(b*2+0)*NTOK + nt*64 + n_l)*NINT + o;
    size_t r1 = ((size_t)(b*2+1)*NTOK + nt*64 + n_l)*NINT + o;
    fs[n_l][o] = feat[r0] + feat[r1];
  }
  __syncthreads();
  float f[64];
  #pragma unroll
  for (int o=0;o<64;o++) f[o] = fs[nl][o];
  int c0 = __builtin_amdgcn_readfirstlane((t>>6)*64);
  const float* wr = wout + (size_t)c0*64;
  for (int cc=0; cc<64; ++cc){
    int c = c0 + cc;
    float acc = x[((size_t)b*NCH + c)*NTOK + nt*64 + nl];
    #pragma unroll
    for (int o=0;o<64;o++) acc += wr[cc*64+o]*f[o];
    out[((size_t)b*NCH + c)*NTOK + nt*64 + nl] = acc;
  }
}

extern "C" void kernel_launch(void* const* d_in, const int* in_sizes, int n_in,
                              void* d_out, int out_size, void* d_ws, size_t ws_size,
                              hipStream_t stream)
{
  const float* x    = (const float*)d_in[0];
  const float* mask = (const float*)d_in[1];
  const float* wts  = (const float*)d_in[2];
  const float* wps  = (const float*)d_in[3];
  const float* wgs  = (const float*)d_in[4];
  const float* wtc  = (const float*)d_in[5];
  const float* wpc  = (const float*)d_in[6];
  const float* wgc  = (const float*)d_in[7];
  const float* wout = (const float*)d_in[8];
  float* out = (float*)d_out;
  char*  ws  = (char*)d_ws;
  (void)in_sizes; (void)n_in; (void)out_size; (void)ws_size;

  k_proj <<<dim3(64,6,NBATCH), 256, 0, stream>>>(x, mask, wts, wps, wgs, wtc, wpc, wgc, ws);
  k_s1   <<<dim3(1024), 256, 0, stream>>>(ws, out);
  k_comb <<<dim3(256),  256, 0, stream>>>(ws, out);
  k_s2   <<<dim3(1024), 256, 0, stream>>>(ws, out);
  k_epi  <<<dim3(64,NBATCH), 256, 0, stream>>>(x, wout, ws, out);
}

// Round 2
// 555.559 us; speedup vs baseline: 1.0509x; 1.0509x over previous
//
#include <hip/hip_runtime.h>
#include <hip/hip_bf16.h>
#include <stdint.h>

#define NBATCH 2
#define NCH    256
#define NTOK   4096
#define NINT   64
#define CHW    64            // staged chunk width (columns)
#define QCOLS  1024          // columns per quarter-block
#define NCHQ   (QCOLS/CHW)   // 16 chunks per quarter

typedef float  f32x4  __attribute__((ext_vector_type(4)));
typedef __bf16 bf16x8 __attribute__((ext_vector_type(8)));
union U16x8 { uint4 u; bf16x8 b; };

// ---- workspace layout (bytes) ----
// per batch, 10 bf16 arrays of [4096][64]: 0 QS_h 1 QS_l 2 KS_h 3 KS_l
// 4 QC_h 5 QC_l 6 KC_h 7 KC_l 8 VS 9 VC
#define SZBF      ((size_t)NTOK*NINT)
// rL (4 bbr x 4096 f32 = 64 KB) overlays V_s of b=0 — dead after k_s1.
#define RL_OFF_B  ((size_t)4194304)

#define OUT_SELF  ((size_t)2097152)
#define OUT_CROSS ((size_t)35651584)
// scratch inside the score_self output region (read by k_rl/k_epi, then
// fully overwritten by k_s2):
#define FPART_OFF_F (OUT_SELF)                     // [4 bbr][4 qtr][4096][64] f32 = 16 MB
#define LPART_OFF_F (OUT_SELF + (size_t)4194304)   // [4 bbr][4 qtr][4096] f32 = 256 KB

__device__ inline unsigned short f2bf(float x){
  unsigned int u = __builtin_bit_cast(unsigned int, x);
  u = (u + 0x7FFFu + ((u>>16)&1u)) >> 16;
  return (unsigned short)u;
}
__device__ inline float bf2f(unsigned short s){
  unsigned int u = ((unsigned int)s)<<16;
  return __builtin_bit_cast(float, u);
}

typedef __attribute__((address_space(3))) unsigned int lds_u32_t;
typedef __attribute__((address_space(1))) const unsigned int gbl_u32_t;
__device__ inline void async16(const void* g, void* l){
  __builtin_amdgcn_global_load_lds((gbl_u32_t*)g, (lds_u32_t*)l, 16, 0, 0);
}
// raw workgroup barrier WITHOUT the compiler's vmcnt(0) drain; IR-level
// memory clobbers on both sides keep loads/stores from crossing it.
__device__ inline void wgbar(){
  asm volatile("" ::: "memory");
  __builtin_amdgcn_s_barrier();
  asm volatile("" ::: "memory");
}

// ---------------- kernel 1: masked projections (fp32) ----------------
__global__ __launch_bounds__(256) void k_proj(
    const float* __restrict__ x, const float* __restrict__ mask,
    const float* __restrict__ wts, const float* __restrict__ wps,
    const float* __restrict__ wgs, const float* __restrict__ wtc,
    const float* __restrict__ wpc, const float* __restrict__ wgc,
    char* __restrict__ ws)
{
  int nt = blockIdx.x;    // 64 n-tiles of 64
  int j  = blockIdx.y;    // which matrix
  int b  = blockIdx.z;
  const float* W; int isBg, mode, arrH, arrL;
  switch (j) {
    case 0: W=wts; isBg=0; mode=0; arrH=2; arrL=3; break; // K_s
    case 1: W=wps; isBg=0; mode=0; arrH=0; arrL=1; break; // Q_s
    case 2: W=wgs; isBg=0; mode=1; arrH=8; arrL=8; break; // V_s
    case 3: W=wpc; isBg=0; mode=0; arrH=4; arrL=5; break; // Q_c
    case 4: W=wtc; isBg=1; mode=0; arrH=6; arrL=7; break; // K_c
    default:W=wgc; isBg=1; mode=1; arrH=9; arrL=9; break; // V_c
  }
  __shared__ float xm[256*64];
  __shared__ float msk[64];
  int t = threadIdx.x;
  if (t < 64) {
    float m = mask[(size_t)b*NTOK + nt*64 + t];
    msk[t] = isBg ? (1.0f - m) : m;
  }
  __syncthreads();
  const float* xb = x + (size_t)b*NCH*NTOK + nt*64;
  for (int it = 0; it < 64; ++it) {
    int flat = it*256 + t; int c = flat>>6, nl = flat&63;
    xm[flat] = xb[(size_t)c*NTOK + nl] * msk[nl];
  }
  __syncthreads();
  int nl = t & 63;
  int o0 = __builtin_amdgcn_readfirstlane((t>>6)*16);
  const float* Wr = W + (size_t)o0*256;
  float acc[16];
  #pragma unroll
  for (int i=0;i<16;i++) acc[i]=0.0f;
  #pragma unroll 4
  for (int c=0;c<256;c++){
    float xv = xm[c*64+nl];
    #pragma unroll
    for (int i=0;i<16;i++) acc[i] += Wr[i*256 + c] * xv;
  }
  int n = nt*64 + nl;
  if (mode==0){
    unsigned short* Ah = (unsigned short*)ws + ((size_t)b*10 + arrH)*SZBF;
    unsigned short* Al = (unsigned short*)ws + ((size_t)b*10 + arrL)*SZBF;
    #pragma unroll
    for (int i=0;i<16;i++){
      float v = acc[i];
      unsigned short h = f2bf(v);
      float r = v - bf2f(h);
      Ah[(size_t)n*NINT + o0+i] = h;
      Al[(size_t)n*NINT + o0+i] = f2bf(r);
    }
  } else {
    unsigned short* V = (unsigned short*)ws + ((size_t)b*10 + arrH)*SZBF;
    #pragma unroll
    for (int i=0;i<16;i++) V[(size_t)(o0+i)*NTOK + n] = f2bf(acc[i]);
  }
}

// ---------------- kernel 2a: sweep 1 on quarter-column blocks ----------------
// 1024 blocks = 4 bbr x 64 mb x 4 qtr; 256 thr = 4 waves. LDS = 40960 B
// (2 x 16 KB K dbuf + 4 x 2 KB lP, granule-XOR-swizzled, no pad) ->
// EXACTLY 4 blocks/CU, zero tail. Raw barrier + explicit vmcnt (no
// compiler drain). Writes UNNORMALIZED feat partials + L partials into
// the (dead) score_self region.
__global__ __launch_bounds__(256) void k_s1(char* __restrict__ ws, float* __restrict__ out)
{
  __shared__ __align__(16) char smem[40960];

  int blk = blockIdx.x;
  int xcd = blk & 7, idx = blk >> 3;
  int bbr = xcd >> 1;                  // 2 XCDs per (b,branch): K/V/Q L2-resident
  int unit = ((xcd & 1) << 7) | idx;   // 0..255
  int qtr = unit & 3, mb = unit >> 2;
  int b = bbr >> 1, br = bbr & 1;
  const unsigned short* Qh = (const unsigned short*)ws + ((size_t)b*10 + (br?4:0))*SZBF;
  const unsigned short* Ql = Qh + SZBF;
  const unsigned short* Kh = (const unsigned short*)ws + ((size_t)b*10 + (br?6:2))*SZBF;
  const unsigned short* Kl = Kh + SZBF;
  const unsigned short* Vv = (const unsigned short*)ws + ((size_t)b*10 + (br?9:8))*SZBF;

  int t = threadIdx.x, lane = t&63, w = t>>6;   // w = m-tile
  int rowb = lane&15, q4 = lane>>4, ko = q4*8;
  int m0 = mb*64 + w*16, mrow = m0 + rowb;

  unsigned short* lPw = (unsigned short*)(smem + 32768 + w*2048);

  U16x8 qh[2], ql[2];
  #pragma unroll
  for (int kk=0;kk<2;kk++){
    qh[kk].u = *(const uint4*)(Qh + (size_t)mrow*NINT + kk*32 + ko);
    ql[kk].u = *(const uint4*)(Ql + (size_t)mrow*NINT + kk*32 + ko);
  }

  auto lkbase = [&](int buf)->unsigned short*{
    return (unsigned short*)(smem + (size_t)buf*16384);
  };
  // stage one 64-col K chunk (KH 8KB + KL 8KB), XOR-swizzled source
  auto stage = [&](int ch, int buf){
    int n0 = qtr*QCOLS + ch*CHW;
    const unsigned short* gH = Kh + (size_t)n0*NINT;
    const unsigned short* gL = Kl + (size_t)n0*NINT;
    unsigned short* LB = lkbase(buf);
    #pragma unroll
    for (int it=0; it<2; ++it){
      int f = it*256 + t;             // granule 0..511
      int r = f>>3, g = f&7, gs = g ^ (r&7);
      size_t goff = (size_t)r*64 + gs*8;
      async16(gH + goff, LB + (size_t)f*8);
      async16(gL + goff, LB + 4096 + (size_t)f*8);
    }
  };

  f32x4 fac[4];
  #pragma unroll
  for (int ot=0;ot<4;ot++) fac[ot] = (f32x4){0.0f,0.0f,0.0f,0.0f};
  float Lacc = 0.0f;

  stage(0, 0);
  for (int ch=0; ch<NCHQ; ++ch){
    int cur = ch & 1;
    asm volatile("s_waitcnt vmcnt(0)" ::: "memory");  // only K stage loads in flight
    wgbar();
    if (ch+1 < NCHQ) stage(ch+1, cur^1);
    asm volatile("" ::: "memory");
    __builtin_amdgcn_sched_barrier(0);
    unsigned short* LB = lkbase(cur);
    int n0 = qtr*QCOLS + ch*CHW;
    #pragma unroll
    for (int t8=0; t8<4; ++t8){
      int row = t8*16 + rowb;
      f32x4 s = {0.0f,0.0f,0.0f,0.0f};
      #pragma unroll
      for (int kk=0; kk<2; ++kk){
        int soff = row*64 + (((kk*4 + q4) ^ (row&7))*8);
        U16x8 ah, al;
        ah.u = *(const uint4*)(LB + soff);
        al.u = *(const uint4*)(LB + 4096 + soff);
        s = __builtin_amdgcn_mfma_f32_16x16x32_bf16(ah.b, qh[kk].b, s, 0,0,0);
        s = __builtin_amdgcn_mfma_f32_16x16x32_bf16(ah.b, ql[kk].b, s, 0,0,0);
        s = __builtin_amdgcn_mfma_f32_16x16x32_bf16(al.b, qh[kk].b, s, 0,0,0);
      }
      float p0=__expf(s[0]), p1=__expf(s[1]), p2=__expf(s[2]), p3=__expf(s[3]);
      Lacc += (p0+p1)+(p2+p3);
      unsigned int lo = (unsigned int)f2bf(p0) | ((unsigned int)f2bf(p1)<<16);
      unsigned int hi = (unsigned int)f2bf(p2) | ((unsigned int)f2bf(p3)<<16);
      uint2 pk; pk.x = lo; pk.y = hi;
      // granule-XOR-swizzled lP: row stride 64 shorts (128B), granule = 16B
      int g  = t8*2 + (q4>>1);
      int gs = g ^ (rowb&7);
      *(uint2*)(lPw + rowb*64 + gs*8 + (q4&1)*4) = pk;
    }
    asm volatile("s_waitcnt lgkmcnt(0)" ::: "memory");
    __builtin_amdgcn_sched_barrier(0);
    #pragma unroll
    for (int kk4=0; kk4<2; ++kk4){
      int rs = (kk4*4 + q4) ^ (rowb&7);
      U16x8 pa;
      pa.u = *(const uint4*)(lPw + rowb*64 + rs*8);
      #pragma unroll
      for (int ot=0; ot<4; ++ot){
        U16x8 vb;
        vb.u = *(const uint4*)(Vv + (size_t)(ot*16+rowb)*NTOK + n0 + kk4*32 + ko);
        fac[ot] = __builtin_amdgcn_mfma_f32_16x16x32_bf16(pa.b, vb.b, fac[ot], 0,0,0);
      }
    }
    asm volatile("s_waitcnt lgkmcnt(0)" ::: "memory");  // lP reads done before next round's writes
  }

  // ---- per-row partial L (this quarter) ----
  #pragma unroll
  for (int d=16; d<64; d<<=1) Lacc += __shfl_xor(Lacc, d, 64);
  if (q4==0)
    out[LPART_OFF_F + (size_t)(bbr*4+qtr)*NTOK + m0 + rowb] = Lacc;

  // ---- unnormalized feat partial (this quarter) ----
  float* FP = out + FPART_OFF_F + (size_t)(bbr*4+qtr)*NTOK*NINT;
  #pragma unroll
  for (int ot=0; ot<4; ++ot)
    #pragma unroll
    for (int r=0; r<4; ++r)
      FP[(size_t)(m0 + q4*4 + r)*NINT + ot*16 + rowb] = fac[ot][r];
}

// ---------------- kernel 2b: 1/L per row (tiny) ----------------
__global__ __launch_bounds__(256) void k_rl(char* __restrict__ ws, const float* __restrict__ out)
{
  int idxg = blockIdx.x*256 + threadIdx.x;     // 0..16383
  int bbr = idxg >> 12, row = idxg & 4095;
  const float* LP = out + LPART_OFF_F;
  float L = 0.0f;
  #pragma unroll
  for (int q=0;q<4;q++) L += LP[(size_t)(bbr*4+q)*NTOK + row];
  ((float*)(ws + RL_OFF_B))[(size_t)bbr*NTOK + row] = 1.0f / L;
}

// ---------------- kernel 3: epilogue out = x + w_out @ (fs+fc) ----------------
// Reads quarter partials + 1/L directly (runs BEFORE k_s2 overwrites them).
__global__ __launch_bounds__(256) void k_epi(
    const float* __restrict__ x, const float* __restrict__ wout,
    const char* __restrict__ ws, float* __restrict__ out)
{
  int nt = blockIdx.x, b = blockIdx.y;
  int t = threadIdx.x, nl = t&63;
  const float* FP = out + FPART_OFF_F;
  const float* rL = (const float*)(ws + RL_OFF_B);
  __shared__ float fs[64][65];
  int b0 = b*2, b1 = b*2+1;
  for (int it=0; it<16; ++it){
    int flat = it*256 + t; int n_l = flat>>6, o = flat&63;
    int row = nt*64 + n_l;
    float s0=0.0f, s1=0.0f;
    #pragma unroll
    for (int q=0;q<4;q++){
      s0 += FP[((size_t)(b0*4+q)*NTOK + row)*NINT + o];
      s1 += FP[((size_t)(b1*4+q)*NTOK + row)*NINT + o];
    }
    fs[n_l][o] = s0*rL[(size_t)b0*NTOK+row] + s1*rL[(size_t)b1*NTOK+row];
  }
  __syncthreads();
  float f[64];
  #pragma unroll
  for (int o=0;o<64;o++) f[o] = fs[nl][o];
  int c0 = __builtin_amdgcn_readfirstlane((t>>6)*64);
  const float* wr = wout + (size_t)c0*64;
  for (int cc=0; cc<64; ++cc){
    int c = c0 + cc;
    float acc = x[((size_t)b*NCH + c)*NTOK + nt*64 + nl];
    #pragma unroll
    for (int o=0;o<64;o++) acc += wr[cc*64+o]*f[o];
    out[((size_t)b*NCH + c)*NTOK + nt*64 + nl] = acc;
  }
}

// ---------------- kernel 4: sweep 2, write P = exp(S)/L ----------------
// Quarter blocks, LDS 32 KB -> 4 resident blocks/CU (cap 5). Raw barrier +
// counted vmcnt(4): only the 4 staging loads are drained each round; the
// previous round's 4 nt-store acks stay in flight (no compiler vmcnt(0)).
__global__ __launch_bounds__(256) void k_s2(const char* __restrict__ ws, float* __restrict__ out)
{
  __shared__ __align__(16) char smem[32768]; // 2 x 16384 K dbuf

  int blk = blockIdx.x;
  int xcd = blk & 7, idx = blk >> 3;
  int bbr = xcd >> 1;
  int unit = ((xcd & 1) << 7) | idx;
  int qtr = unit & 3, mb = unit >> 2;
  int b = bbr >> 1, br = bbr & 1;
  const unsigned short* Qh = (const unsigned short*)ws + ((size_t)b*10 + (br?4:0))*SZBF;
  const unsigned short* Ql = Qh + SZBF;
  const unsigned short* Kh = (const unsigned short*)ws + ((size_t)b*10 + (br?6:2))*SZBF;
  const unsigned short* Kl = Kh + SZBF;

  int t = threadIdx.x, lane = t&63, w = t>>6;
  int rowb = lane&15, q4 = lane>>4, ko = q4*8;
  int m0 = mb*64 + w*16, mrow = m0 + rowb;

  float rLp = ((const float*)(ws + RL_OFF_B))[(size_t)bbr*NTOK + mrow];

  U16x8 qh[2], ql[2];
  #pragma unroll
  for (int kk=0;kk<2;kk++){
    qh[kk].u = *(const uint4*)(Qh + (size_t)mrow*NINT + kk*32 + ko);
    ql[kk].u = *(const uint4*)(Ql + (size_t)mrow*NINT + kk*32 + ko);
  }

  auto lkbase = [&](int buf)->unsigned short*{
    return (unsigned short*)(smem + (size_t)buf*16384);
  };
  auto stage = [&](int ch, int buf){
    int n0 = qtr*QCOLS + ch*CHW;
    const unsigned short* gH = Kh + (size_t)n0*NINT;
    const unsigned short* gL = Kl + (size_t)n0*NINT;
    unsigned short* LB = lkbase(buf);
    #pragma unroll
    for (int it=0; it<2; ++it){
      int f = it*256 + t;
      int r = f>>3, g = f&7, gs = g ^ (r&7);
      size_t goff = (size_t)r*64 + gs*8;
      async16(gH + goff, LB + (size_t)f*8);
      async16(gL + goff, LB + 4096 + (size_t)f*8);
    }
  };

  float* outS = out + (br ? OUT_CROSS : OUT_SELF) + (size_t)b*NTOK*NTOK;

  stage(0, 0);
  for (int ch=0; ch<NCHQ; ++ch){
    int cur = ch & 1;
    if (ch == 0) { asm volatile("s_waitcnt vmcnt(0)" ::: "memory"); }
    else         { asm volatile("s_waitcnt vmcnt(4)" ::: "memory"); }
    wgbar();
    if (ch+1 < NCHQ) stage(ch+1, cur^1);
    asm volatile("" ::: "memory");
    __builtin_amdgcn_sched_barrier(0);   // pin: stage loads issue before this round's stores
    unsigned short* LB = lkbase(cur);
    int n0 = qtr*QCOLS + ch*CHW;
    #pragma unroll
    for (int t8=0; t8<4; ++t8){
      int row = t8*16 + rowb;
      f32x4 s = {0.0f,0.0f,0.0f,0.0f};
      #pragma unroll
      for (int kk=0; kk<2; ++kk){
        int soff = row*64 + (((kk*4 + q4) ^ (row&7))*8);
        U16x8 ah, al;
        ah.u = *(const uint4*)(LB + soff);
        al.u = *(const uint4*)(LB + 4096 + soff);
        s = __builtin_amdgcn_mfma_f32_16x16x32_bf16(ah.b, qh[kk].b, s, 0,0,0);
        s = __builtin_amdgcn_mfma_f32_16x16x32_bf16(ah.b, ql[kk].b, s, 0,0,0);
        s = __builtin_amdgcn_mfma_f32_16x16x32_bf16(al.b, qh[kk].b, s, 0,0,0);
      }
      f32x4 p;
      p[0] = __expf(s[0])*rLp; p[1] = __expf(s[1])*rLp;
      p[2] = __expf(s[2])*rLp; p[3] = __expf(s[3])*rLp;
      __builtin_nontemporal_store(p,
          (f32x4*)(outS + (size_t)mrow*NTOK + n0 + t8*16 + q4*4));
    }
  }
}

extern "C" void kernel_launch(void* const* d_in, const int* in_sizes, int n_in,
                              void* d_out, int out_size, void* d_ws, size_t ws_size,
                              hipStream_t stream)
{
  const float* x    = (const float*)d_in[0];
  const float* mask = (const float*)d_in[1];
  const float* wts  = (const float*)d_in[2];
  const float* wps  = (const float*)d_in[3];
  const float* wgs  = (const float*)d_in[4];
  const float* wtc  = (const float*)d_in[5];
  const float* wpc  = (const float*)d_in[6];
  const float* wgc  = (const float*)d_in[7];
  const float* wout = (const float*)d_in[8];
  float* out = (float*)d_out;
  char*  ws  = (char*)d_ws;
  (void)in_sizes; (void)n_in; (void)out_size; (void)ws_size;

  k_proj <<<dim3(64,6,NBATCH), 256, 0, stream>>>(x, mask, wts, wps, wgs, wtc, wpc, wgc, ws);
  k_s1   <<<dim3(1024), 256, 0, stream>>>(ws, out);
  k_rl   <<<dim3(64),   256, 0, stream>>>(ws, out);
  k_epi  <<<dim3(64,NBATCH), 256, 0, stream>>>(x, wout, ws, out);  // before k_s2 (reads FPART)
  k_s2   <<<dim3(1024), 256, 0, stream>>>(ws, out);
}